// Round 11
// baseline (135.054 us; speedup 1.0000x reference)
//
#include <hip/hip_runtime.h>

namespace {

constexpr int T   = 30;
constexpr int C   = 4;
constexpr int HW  = 256 * 256;
constexpr int B   = 8;
constexpr int CHW = C * HW;

typedef _Float16 f16x2 __attribute__((ext_vector_type(2)));

// R10 structure exactly (cached loads for L3 residency across replays,
// nt stores so the output stream doesn't evict inputs, explicit v[30]
// load batch + sched_barrier(0) so the backend keeps all 30 in flight),
// single change: waves_per_eu(4,4) -> (8,8). R10 measured VGPR=64 with
// zero spill, so the kernel already fits the 64-reg/8-waves budget; the
// (4,4) pin was capping residency at half of what the reg file allows.
// 32 waves/CU doubles the wave contexts interleaving each channel's
// load-batch latency window.
__global__ __attribute__((amdgpu_flat_work_group_size(256, 256)))
           __attribute__((amdgpu_waves_per_eu(8, 8)))
void interp_kernel(
    const float* __restrict__ images,
    const float* __restrict__ mask,
    const float* __restrict__ days,
    float* __restrict__ out)
{
    __shared__ float s_day[T];
    const int tid = threadIdx.x;
    const int b   = blockIdx.x >> 8;            // 256 blocks per batch image
    if (tid < T) s_day[tid] = days[b * T + tid];
    __syncthreads();

    const int hw = ((blockIdx.x & 255) << 8) | tid;

    // ---- visibility bitmask: 30 batched cached loads ----
    const float* mbase = mask + (size_t)b * T * HW + hw;
    unsigned vis = 0u;
    {
        float mv[T];
#pragma unroll
        for (int t = 0; t < T; ++t) mv[t] = mbase[(size_t)t * HW];
        __builtin_amdgcn_sched_barrier(0);
#pragma unroll
        for (int t = 0; t < T; ++t) vis |= (mv[t] == 0.0f ? 1u : 0u) << t;
    }

    // ---- fr[]: backward day-of-next-visible scan (f16 exact: integer
    //      days), then transformed in place to frac on the forward pass ----
    f16x2 fr[T / 2];
    {
        float run = 0.0f;
#pragma unroll
        for (int t = T - 1; t >= 0; --t) {
            run = ((vis >> t) & 1u) ? s_day[t] : run;
            if (t & 1) fr[t >> 1].y = (_Float16)run;
            else       fr[t >> 1].x = (_Float16)run;
        }
        float dl = 0.0f;
#pragma unroll
        for (int t = 0; t < T; ++t) {
            const float d = s_day[t];
            dl = ((vis >> t) & 1u) ? d : dl;
            const float dn = (t & 1) ? (float)fr[t >> 1].y
                                     : (float)fr[t >> 1].x;
            float den = dn - dl;
            den = (den == 0.0f) ? 1.0f : den;
            float f = (d - dl) / den;
            const bool lv_ok = (vis & ((1u << (t + 1)) - 1u)) != 0u;
            const bool nv_ok = (vis >> t) != 0u;
            // visible/only_last/none -> 0 ; only_next -> 1 (rl==0 => img_next)
            f = (lv_ok && nv_ok) ? f : (nv_ok ? 1.0f : 0.0f);
            if (t & 1) fr[t >> 1].y = (_Float16)f;
            else       fr[t >> 1].x = (_Float16)f;
        }
    }

    const bool  none = (vis == 0u);
    const float nanv = __int_as_float(0x7fc00000);
    const size_t pixBase = (size_t)b * T * CHW + hw;

#pragma unroll 1
    for (int c = 0; c < C; ++c) {
        const float* ib = images + pixBase + (size_t)c * HW;
        float*       ob = out    + pixBase + (size_t)c * HW;

        // 30 batched cached loads into an explicit live array
        float v[T];
#pragma unroll
        for (int t = 0; t < T; ++t) v[t] = ib[(size_t)t * CHW];
        __builtin_amdgcn_sched_barrier(0);

        // backward value-scan; nv packed f16x2
        f16x2 nvp[T / 2];
        {
            float run = 0.0f;
#pragma unroll
            for (int t = T - 1; t >= 0; --t) {
                run = ((vis >> t) & 1u) ? v[t] : run;
                if (t & 1) nvp[t >> 1].y = (_Float16)run;
                else       nvp[t >> 1].x = (_Float16)run;
            }
        }
        // forward scan (rl = nv[t] at visible t) + blend + nt store
        {
            float rl = 0.0f;
#pragma unroll
            for (int t = 0; t < T; ++t) {
                const float nv = (t & 1) ? (float)nvp[t >> 1].y
                                         : (float)nvp[t >> 1].x;
                rl = ((vis >> t) & 1u) ? nv : rl;
                const float f  = (t & 1) ? (float)fr[t >> 1].y
                                         : (float)fr[t >> 1].x;
                const float res = fmaf(f, nv - rl, rl);
                __builtin_nontemporal_store(none ? nanv : res,
                                            &ob[(size_t)t * CHW]);
            }
        }
    }
}

} // namespace

extern "C" void kernel_launch(void* const* d_in, const int* in_sizes, int n_in,
                              void* d_out, int out_size, void* d_ws, size_t ws_size,
                              hipStream_t stream)
{
    const float* images = (const float*)d_in[0];
    const float* mask   = (const float*)d_in[1];
    const float* days   = (const float*)d_in[2];
    float* out          = (float*)d_out;

    const int nPix = B * HW;                 // one thread per (b, h, w)
    dim3 grid(nPix / 256), block(256);
    hipLaunchKernelGGL(interp_kernel, grid, block, 0, stream,
                       images, mask, days, out);
}

// Round 12
// 116.511 us; speedup vs baseline: 1.1592x; 1.1592x over previous
//
#include <hip/hip_runtime.h>

namespace {

constexpr int T   = 30;
constexpr int C   = 4;
constexpr int HW  = 256 * 256;
constexpr int B   = 8;
constexpr int CHW = C * HW;

typedef _Float16 f16x2 __attribute__((ext_vector_type(2)));

// R10 structure exactly (cached loads for L3 residency across replays,
// nt stores so the output stream doesn't evict inputs, explicit v[30]
// load batch + sched_barrier(0)), single change: waves_per_eu(4,4) ->
// (6,6). Budget floor(512/6)=84 VGPR > the proven 64-reg fit, so codegen
// should be identical to R10 (VGPR=64, zero spill) while the occupancy
// cap rises 16 -> 24 waves/CU. Isolates occupancy without R11's spill
// confounder (its (8,8) pin squeezed to 32 regs, +110 MB scratch).
__global__ __attribute__((amdgpu_flat_work_group_size(256, 256)))
           __attribute__((amdgpu_waves_per_eu(6, 6)))
void interp_kernel(
    const float* __restrict__ images,
    const float* __restrict__ mask,
    const float* __restrict__ days,
    float* __restrict__ out)
{
    __shared__ float s_day[T];
    const int tid = threadIdx.x;
    const int b   = blockIdx.x >> 8;            // 256 blocks per batch image
    if (tid < T) s_day[tid] = days[b * T + tid];
    __syncthreads();

    const int hw = ((blockIdx.x & 255) << 8) | tid;

    // ---- visibility bitmask: 30 batched cached loads ----
    const float* mbase = mask + (size_t)b * T * HW + hw;
    unsigned vis = 0u;
    {
        float mv[T];
#pragma unroll
        for (int t = 0; t < T; ++t) mv[t] = mbase[(size_t)t * HW];
        __builtin_amdgcn_sched_barrier(0);
#pragma unroll
        for (int t = 0; t < T; ++t) vis |= (mv[t] == 0.0f ? 1u : 0u) << t;
    }

    // ---- fr[]: backward day-of-next-visible scan (f16 exact: integer
    //      days), then transformed in place to frac on the forward pass ----
    f16x2 fr[T / 2];
    {
        float run = 0.0f;
#pragma unroll
        for (int t = T - 1; t >= 0; --t) {
            run = ((vis >> t) & 1u) ? s_day[t] : run;
            if (t & 1) fr[t >> 1].y = (_Float16)run;
            else       fr[t >> 1].x = (_Float16)run;
        }
        float dl = 0.0f;
#pragma unroll
        for (int t = 0; t < T; ++t) {
            const float d = s_day[t];
            dl = ((vis >> t) & 1u) ? d : dl;
            const float dn = (t & 1) ? (float)fr[t >> 1].y
                                     : (float)fr[t >> 1].x;
            float den = dn - dl;
            den = (den == 0.0f) ? 1.0f : den;
            float f = (d - dl) / den;
            const bool lv_ok = (vis & ((1u << (t + 1)) - 1u)) != 0u;
            const bool nv_ok = (vis >> t) != 0u;
            // visible/only_last/none -> 0 ; only_next -> 1 (rl==0 => img_next)
            f = (lv_ok && nv_ok) ? f : (nv_ok ? 1.0f : 0.0f);
            if (t & 1) fr[t >> 1].y = (_Float16)f;
            else       fr[t >> 1].x = (_Float16)f;
        }
    }

    const bool  none = (vis == 0u);
    const float nanv = __int_as_float(0x7fc00000);
    const size_t pixBase = (size_t)b * T * CHW + hw;

#pragma unroll 1
    for (int c = 0; c < C; ++c) {
        const float* ib = images + pixBase + (size_t)c * HW;
        float*       ob = out    + pixBase + (size_t)c * HW;

        // 30 batched cached loads into an explicit live array
        float v[T];
#pragma unroll
        for (int t = 0; t < T; ++t) v[t] = ib[(size_t)t * CHW];
        __builtin_amdgcn_sched_barrier(0);

        // backward value-scan; nv packed f16x2
        f16x2 nvp[T / 2];
        {
            float run = 0.0f;
#pragma unroll
            for (int t = T - 1; t >= 0; --t) {
                run = ((vis >> t) & 1u) ? v[t] : run;
                if (t & 1) nvp[t >> 1].y = (_Float16)run;
                else       nvp[t >> 1].x = (_Float16)run;
            }
        }
        // forward scan (rl = nv[t] at visible t) + blend + nt store
        {
            float rl = 0.0f;
#pragma unroll
            for (int t = 0; t < T; ++t) {
                const float nv = (t & 1) ? (float)nvp[t >> 1].y
                                         : (float)nvp[t >> 1].x;
                rl = ((vis >> t) & 1u) ? nv : rl;
                const float f  = (t & 1) ? (float)fr[t >> 1].y
                                         : (float)fr[t >> 1].x;
                const float res = fmaf(f, nv - rl, rl);
                __builtin_nontemporal_store(none ? nanv : res,
                                            &ob[(size_t)t * CHW]);
            }
        }
    }
}

} // namespace

extern "C" void kernel_launch(void* const* d_in, const int* in_sizes, int n_in,
                              void* d_out, int out_size, void* d_ws, size_t ws_size,
                              hipStream_t stream)
{
    const float* images = (const float*)d_in[0];
    const float* mask   = (const float*)d_in[1];
    const float* days   = (const float*)d_in[2];
    float* out          = (float*)d_out;

    const int nPix = B * HW;                 // one thread per (b, h, w)
    dim3 grid(nPix / 256), block(256);
    hipLaunchKernelGGL(interp_kernel, grid, block, 0, stream,
                       images, mask, days, out);
}

// Round 13
// 103.427 us; speedup vs baseline: 1.3058x; 1.1265x over previous
//
#include <hip/hip_runtime.h>

namespace {

constexpr int T   = 30;
constexpr int C   = 4;
constexpr int HW  = 256 * 256;
constexpr int B   = 8;
constexpr int CHW = C * HW;

typedef _Float16 f16x2 __attribute__((ext_vector_type(2)));

// R10 base (cached loads -> L3 residency across replays, nt stores,
// batched loads + sched_barrier(0), f16x2-packed scan arrays, (4,4) pin
// = the only spill-free allocator operating point). Change vs R10:
// channels processed in PAIRS -- all 60 loads of two channels issued as
// one batch, then scan+store ch0 (VALU overlaps ch1's in-flight loads),
// then scan+store ch1. Interior full-latency stall windows drop 3 -> 1.
// Peak live ~105 VGPR fits the 128-reg budget.
__global__ __attribute__((amdgpu_flat_work_group_size(256, 256)))
           __attribute__((amdgpu_waves_per_eu(4, 4)))
void interp_kernel(
    const float* __restrict__ images,
    const float* __restrict__ mask,
    const float* __restrict__ days,
    float* __restrict__ out)
{
    __shared__ float s_day[T];
    const int tid = threadIdx.x;
    const int b   = blockIdx.x >> 8;            // 256 blocks per batch image
    if (tid < T) s_day[tid] = days[b * T + tid];
    __syncthreads();

    const int hw = ((blockIdx.x & 255) << 8) | tid;

    // ---- visibility bitmask: 30 batched cached loads ----
    const float* mbase = mask + (size_t)b * T * HW + hw;
    unsigned vis = 0u;
    {
        float mv[T];
#pragma unroll
        for (int t = 0; t < T; ++t) mv[t] = mbase[(size_t)t * HW];
        __builtin_amdgcn_sched_barrier(0);
#pragma unroll
        for (int t = 0; t < T; ++t) vis |= (mv[t] == 0.0f ? 1u : 0u) << t;
    }

    // ---- fr[]: backward day-of-next-visible scan (f16 exact: integer
    //      days), then transformed in place to frac on the forward pass ----
    f16x2 fr[T / 2];
    {
        float run = 0.0f;
#pragma unroll
        for (int t = T - 1; t >= 0; --t) {
            run = ((vis >> t) & 1u) ? s_day[t] : run;
            if (t & 1) fr[t >> 1].y = (_Float16)run;
            else       fr[t >> 1].x = (_Float16)run;
        }
        float dl = 0.0f;
#pragma unroll
        for (int t = 0; t < T; ++t) {
            const float d = s_day[t];
            dl = ((vis >> t) & 1u) ? d : dl;
            const float dn = (t & 1) ? (float)fr[t >> 1].y
                                     : (float)fr[t >> 1].x;
            float den = dn - dl;
            den = (den == 0.0f) ? 1.0f : den;
            float f = (d - dl) / den;
            const bool lv_ok = (vis & ((1u << (t + 1)) - 1u)) != 0u;
            const bool nv_ok = (vis >> t) != 0u;
            // visible/only_last/none -> 0 ; only_next -> 1 (rl==0 => img_next)
            f = (lv_ok && nv_ok) ? f : (nv_ok ? 1.0f : 0.0f);
            if (t & 1) fr[t >> 1].y = (_Float16)f;
            else       fr[t >> 1].x = (_Float16)f;
        }
    }

    const bool  none = (vis == 0u);
    const float nanv = __int_as_float(0x7fc00000);
    const size_t pixBase = (size_t)b * T * CHW + hw;

#pragma unroll 1
    for (int cp = 0; cp < C / 2; ++cp) {
        const int c0 = cp * 2;
        const float* ib0 = images + pixBase + (size_t)c0 * HW;
        const float* ib1 = ib0 + HW;
        float*       ob0 = out    + pixBase + (size_t)c0 * HW;
        float*       ob1 = ob0 + HW;

        // 60 batched cached loads (two channels) into explicit live arrays
        float v0[T], v1[T];
#pragma unroll
        for (int t = 0; t < T; ++t) v0[t] = ib0[(size_t)t * CHW];
#pragma unroll
        for (int t = 0; t < T; ++t) v1[t] = ib1[(size_t)t * CHW];
        __builtin_amdgcn_sched_barrier(0);

        // ---- channel 0: scan + store (ch1 loads still in flight) ----
        {
            f16x2 nvp[T / 2];
            float run = 0.0f;
#pragma unroll
            for (int t = T - 1; t >= 0; --t) {
                run = ((vis >> t) & 1u) ? v0[t] : run;
                if (t & 1) nvp[t >> 1].y = (_Float16)run;
                else       nvp[t >> 1].x = (_Float16)run;
            }
            float rl = 0.0f;
#pragma unroll
            for (int t = 0; t < T; ++t) {
                const float nv = (t & 1) ? (float)nvp[t >> 1].y
                                         : (float)nvp[t >> 1].x;
                rl = ((vis >> t) & 1u) ? nv : rl;
                const float f  = (t & 1) ? (float)fr[t >> 1].y
                                         : (float)fr[t >> 1].x;
                const float res = fmaf(f, nv - rl, rl);
                __builtin_nontemporal_store(none ? nanv : res,
                                            &ob0[(size_t)t * CHW]);
            }
        }
        // ---- channel 1: scan + store ----
        {
            f16x2 nvp[T / 2];
            float run = 0.0f;
#pragma unroll
            for (int t = T - 1; t >= 0; --t) {
                run = ((vis >> t) & 1u) ? v1[t] : run;
                if (t & 1) nvp[t >> 1].y = (_Float16)run;
                else       nvp[t >> 1].x = (_Float16)run;
            }
            float rl = 0.0f;
#pragma unroll
            for (int t = 0; t < T; ++t) {
                const float nv = (t & 1) ? (float)nvp[t >> 1].y
                                         : (float)nvp[t >> 1].x;
                rl = ((vis >> t) & 1u) ? nv : rl;
                const float f  = (t & 1) ? (float)fr[t >> 1].y
                                         : (float)fr[t >> 1].x;
                const float res = fmaf(f, nv - rl, rl);
                __builtin_nontemporal_store(none ? nanv : res,
                                            &ob1[(size_t)t * CHW]);
            }
        }
    }
}

} // namespace

extern "C" void kernel_launch(void* const* d_in, const int* in_sizes, int n_in,
                              void* d_out, int out_size, void* d_ws, size_t ws_size,
                              hipStream_t stream)
{
    const float* images = (const float*)d_in[0];
    const float* mask   = (const float*)d_in[1];
    const float* days   = (const float*)d_in[2];
    float* out          = (float*)d_out;

    const int nPix = B * HW;                 // one thread per (b, h, w)
    dim3 grid(nPix / 256), block(256);
    hipLaunchKernelGGL(interp_kernel, grid, block, 0, stream,
                       images, mask, days, out);
}